// Round 16
// baseline (104.794 us; speedup 1.0000x reference)
//
#include <hip/hip_runtime.h>

// Capsule routing, MI355X. B=2048, I=64, O=32, DI=DO=16, 3 iters.
// R16 = R15's MFMA A-phase (fragment layouts HW-verified by R15's pass)
// with the p path rebuilt around the MFMA output shape:
//   * acc[0..3] = d=4dq..4dq+3 for b=lane&15 -> ONE b128 store per i into
//     p[i][b][dq] 16B units, slot = (((4b+dq) ^ (4*(b>>2))) + i + (i>>3)) & 31.
//     Writer active groups {p,p+16,p+32,p+48}: b const, dq 0..3 -> 4 distinct
//     quads (conflict-free). Bijective per i-row (XOR maps b>=4 -> b^1).
//   * B-phase: 16 b32 reads/thread, quad = c + dq + 2q -> 2-way (free, m136).
// A-frag NOW packs [Whi | Wlo] over K=32 (32 VGPR, half of R15): per i two
//   B-frags (per plane, k-octets dup'd) chained: mfma(A,Blo,mfma(A,Bhi,0))
//   = (Whi+Wlo)(xhi+xlo). x_t layout/staging = R15 verbatim (derived free).
// B-phase softmax/out = R14 verbatim. W' = rw+ns precomputed (wsum).
// Straight-line, constant-indexed (R7); no min-wave forcing (R2/R5).

#define THREADS 512

typedef __attribute__((ext_vector_type(8))) short bf16x8;
typedef __attribute__((ext_vector_type(4))) float f32x4;

__device__ __forceinline__ unsigned hi_bits(float v) {
    return __float_as_uint(v) & 0xFFFF0000u;
}
__device__ __forceinline__ unsigned lo_u(float v) {
    return __float_as_uint(v - __uint_as_float(hi_bits(v)));
}

__global__ __launch_bounds__(256) void wsum_kernel(
    const float* __restrict__ rw, const float* __restrict__ ns,
    float* __restrict__ w2)
{
    const int i = blockIdx.x * 256 + threadIdx.x;   // 131072 float4s
    const float4 a = reinterpret_cast<const float4*>(rw)[i];
    const float4 n = reinterpret_cast<const float4*>(ns)[i];
    float4 r;
    r.x = a.x + n.x;  r.y = a.y + n.y;  r.z = a.z + n.z;  r.w = a.w + n.w;
    reinterpret_cast<float4*>(w2)[i] = r;
}

template <bool PRE>
__global__ __launch_bounds__(THREADS) void routing_kernel(
    const float* __restrict__ x,    // (B, DI, I) = (2048,16,64)
    const float* __restrict__ rw,   // PRE ? W' : rw   (O,I,DO,DI)
    const float* __restrict__ ns,   // unused if PRE
    float* __restrict__ out)        // (1, O, B, DO)
{
    extern __shared__ float lds[];  // bytes [0,32768) p; [32768,65536) x_t

    const int tid  = threadIdx.x;
    const int w    = tid >> 6;      // wave 0..7
    const int lane = tid & 63;

    const int o  = blockIdx.x >> 5;   // o-major
    const int bc = blockIdx.x & 31;   // 64-b chunk
    const int bbase = bc * 64;

    // ---- A-frags: A[d][k] = k<16 ? Whi[d][k] : Wlo[d][k-16]; i = 8w+t ----
    bf16x8 afr[8];
    {
        const int dA  = lane & 15;
        const int koA = lane >> 4;
        const int e0A = (koA & 1) * 8;
        const bool hiA = koA < 2;
        const int wb = ((o * 64 + 8 * w) * 16 + dA) * 16 + e0A;
        #pragma unroll
        for (int t = 0; t < 8; ++t) {
            float4 f0 = *reinterpret_cast<const float4*>(rw + wb + t * 256);
            float4 f1 = *reinterpret_cast<const float4*>(rw + wb + t * 256 + 4);
            if (!PRE) {
                const float4 n0 = *reinterpret_cast<const float4*>(ns + wb + t * 256);
                const float4 n1 = *reinterpret_cast<const float4*>(ns + wb + t * 256 + 4);
                f0.x += n0.x; f0.y += n0.y; f0.z += n0.z; f0.w += n0.w;
                f1.x += n1.x; f1.y += n1.y; f1.z += n1.z; f1.w += n1.w;
            }
            const unsigned v0 = hiA ? __float_as_uint(f0.x) : lo_u(f0.x);
            const unsigned v1 = hiA ? __float_as_uint(f0.y) : lo_u(f0.y);
            const unsigned v2 = hiA ? __float_as_uint(f0.z) : lo_u(f0.z);
            const unsigned v3 = hiA ? __float_as_uint(f0.w) : lo_u(f0.w);
            const unsigned v4 = hiA ? __float_as_uint(f1.x) : lo_u(f1.x);
            const unsigned v5 = hiA ? __float_as_uint(f1.y) : lo_u(f1.y);
            const unsigned v6 = hiA ? __float_as_uint(f1.z) : lo_u(f1.z);
            const unsigned v7 = hiA ? __float_as_uint(f1.w) : lo_u(f1.w);
            afr[t][0] = (short)(v0 >> 16);  afr[t][1] = (short)(v1 >> 16);
            afr[t][2] = (short)(v2 >> 16);  afr[t][3] = (short)(v3 >> 16);
            afr[t][4] = (short)(v4 >> 16);  afr[t][5] = (short)(v5 >> 16);
            afr[t][6] = (short)(v6 >> 16);  afr[t][7] = (short)(v7 >> 16);
        }
    }

    // ---- x_t read ptrs (R15 layout): unit = (4b + 2eo + pl) ^ ((i>>3)&7) ----
    const int bxB = lane & 7;
    const int eoB = (lane >> 4) & 1;
    const char* xtb = reinterpret_cast<const char*>(lds) + 32768 + w * 4096;
    const char* rdhi = xtb + (((4 * bxB + 2 * eoB + 0) ^ w) << 4);
    const char* rdlo = xtb + (((4 * bxB + 2 * eoB + 1) ^ w) << 4);

    // ---- p store: lane (b=lane&7, dq=lane>>4), active lane&15 < 8 ----
    const int pbS  = lane & 7;
    const int pdqS = lane >> 4;
    const bool pact = (lane & 8) == 0;
    const int pslot0 = (((4 * pbS + pdqS) ^ (4 * (pbS >> 2))) + 9 * w);
    char* pstA = reinterpret_cast<char*>(lds) + 8 * w * 512;   // i-row t=0

    // ---- B-phase p reads: thread (b=w, d=lane&15, q=lane>>4) ----
    const int qB = lane >> 4;
    const int dB = lane & 15;
    const int dqR = dB >> 2;
    const int c0 = (((4 * w + dqR) ^ (4 * (w >> 2))) + 18 * qB);
    const char* pb0 = reinterpret_cast<const char*>(lds) + qB * 8192
                    + (dB & 3) * 4;

    const int outbase = (o * 2048 + bbase + w) * 16 + dB;

    // ---- staging (R15 verbatim): thread (b=w, i=lane) ----
    const int kskew = (lane >> 3) & 7;
    char* xt_wr = reinterpret_cast<char*>(lds) + 32768 + lane * 512;
    const int ow00 = ((w * 4 + 0) ^ kskew) << 4;   // eo0, hi
    const int ow01 = ((w * 4 + 1) ^ kskew) << 4;   // eo0, lo
    const int ow10 = ((w * 4 + 2) ^ kskew) << 4;   // eo1, hi
    const int ow11 = ((w * 4 + 3) ^ kskew) << 4;   // eo1, lo
    const float* xsrc = x + (bbase + w) * 1024 + lane;

    // ---- prologue: stage tile 0 ----
    {
        float v[16];
        #pragma unroll
        for (int e = 0; e < 16; ++e) v[e] = xsrc[e * 64];
        unsigned h0 = (__float_as_uint(v[0]) >> 16) | hi_bits(v[1]);
        unsigned h1 = (__float_as_uint(v[2]) >> 16) | hi_bits(v[3]);
        unsigned h2 = (__float_as_uint(v[4]) >> 16) | hi_bits(v[5]);
        unsigned h3 = (__float_as_uint(v[6]) >> 16) | hi_bits(v[7]);
        unsigned h4 = (__float_as_uint(v[8]) >> 16) | hi_bits(v[9]);
        unsigned h5 = (__float_as_uint(v[10]) >> 16) | hi_bits(v[11]);
        unsigned h6 = (__float_as_uint(v[12]) >> 16) | hi_bits(v[13]);
        unsigned h7 = (__float_as_uint(v[14]) >> 16) | hi_bits(v[15]);
        unsigned l0 = (lo_u(v[0]) >> 16) | (lo_u(v[1]) & 0xFFFF0000u);
        unsigned l1 = (lo_u(v[2]) >> 16) | (lo_u(v[3]) & 0xFFFF0000u);
        unsigned l2 = (lo_u(v[4]) >> 16) | (lo_u(v[5]) & 0xFFFF0000u);
        unsigned l3 = (lo_u(v[6]) >> 16) | (lo_u(v[7]) & 0xFFFF0000u);
        unsigned l4 = (lo_u(v[8]) >> 16) | (lo_u(v[9]) & 0xFFFF0000u);
        unsigned l5 = (lo_u(v[10]) >> 16) | (lo_u(v[11]) & 0xFFFF0000u);
        unsigned l6 = (lo_u(v[12]) >> 16) | (lo_u(v[13]) & 0xFFFF0000u);
        unsigned l7 = (lo_u(v[14]) >> 16) | (lo_u(v[15]) & 0xFFFF0000u);
        *reinterpret_cast<uint4*>(xt_wr + ow00) = make_uint4(h0, h1, h2, h3);
        *reinterpret_cast<uint4*>(xt_wr + ow01) = make_uint4(l0, l1, l2, l3);
        *reinterpret_cast<uint4*>(xt_wr + ow10) = make_uint4(h4, h5, h6, h7);
        *reinterpret_cast<uint4*>(xt_wr + ow11) = make_uint4(l4, l5, l6, l7);
    }
    __syncthreads();                // x_t(0) ready

    #pragma unroll
    for (int s = 0; s < 8; ++s) {
        // ---- A-phase: per i = 8w+t: 2 b128 B-frag reads, 2 MFMA, 1 b128 p-store
        #pragma unroll
        for (int t = 0; t < 8; ++t) {
            const bf16x8 bhi = *reinterpret_cast<const bf16x8*>(rdhi + t * 512);
            const bf16x8 blo = *reinterpret_cast<const bf16x8*>(rdlo + t * 512);
            f32x4 acc = {0.f, 0.f, 0.f, 0.f};
            acc = __builtin_amdgcn_mfma_f32_16x16x32_bf16(afr[t], blo, acc, 0, 0, 0);
            acc = __builtin_amdgcn_mfma_f32_16x16x32_bf16(afr[t], bhi, acc, 0, 0, 0);
            if (pact) {
                const int sl = (pslot0 + t) & 31;
                *reinterpret_cast<float4*>(pstA + t * 512 + (sl << 4)) =
                    make_float4(acc[0], acc[1], acc[2], acc[3]);
            }
        }
        __syncthreads();            // p ready; x_t consumed

        // ---- B-read: p[g] = priors[b=w, i=qB*16+g, dB], 16 b32 (2-way free)
        float p[16];
        #pragma unroll
        for (int g = 0; g < 16; ++g) {
            const int sl = (c0 + g + (g >> 3)) & 31;
            p[g] = *reinterpret_cast<const float*>(pb0 + g * 512 + (sl << 4));
        }

        // ---- T14 issue-early: next tile e=0..7 ----
        float se[8];
        if (s < 7) {
            const float* xs = xsrc + (s + 1) * 8192;
            se[0] = xs[0];   se[1] = xs[64];  se[2] = xs[128]; se[3] = xs[192];
            se[4] = xs[256]; se[5] = xs[320]; se[6] = xs[384]; se[7] = xs[448];
        }

        // ---- routing iterations (R14 verbatim) ----
        float t0 = (p[0]+p[1]) + (p[2]+p[3]);
        float t1 = (p[4]+p[5]) + (p[6]+p[7]);
        float t2 = (p[8]+p[9]) + (p[10]+p[11]);
        float t3 = (p[12]+p[13]) + (p[14]+p[15]);
        float part = (t0 + t1) + (t2 + t3);
        part += __shfl_xor(part, 16);
        part += __shfl_xor(part, 32);
        float sv = part * (1.0f / 64.0f);

        float sn = sv * sv;
        sn += __shfl_xor(sn, 1); sn += __shfl_xor(sn, 2);
        sn += __shfl_xor(sn, 4); sn += __shfl_xor(sn, 8);
        float factor = __builtin_amdgcn_sqrtf(sn)
                     * __builtin_amdgcn_rcpf(1.0f + sn);
        float Vsum = sv * factor;

        #pragma unroll
        for (int it = 0; it < 2; ++it) {
            const float c = Vsum * 1.44269504089f;
            float e0, e1, e2, e3;
            float dd0, dd1, dd2, dd3, nn0, nn1, nn2, nn3;
            e0 = __builtin_amdgcn_exp2f(p[0] * c);
            e1 = __builtin_amdgcn_exp2f(p[1] * c);
            e2 = __builtin_amdgcn_exp2f(p[2] * c);
            e3 = __builtin_amdgcn_exp2f(p[3] * c);
            dd0 = e0; dd1 = e1; dd2 = e2; dd3 = e3;
            nn0 = e0 * p[0]; nn1 = e1 * p[1]; nn2 = e2 * p[2]; nn3 = e3 * p[3];
            e0 = __builtin_amdgcn_exp2f(p[4] * c);
            e1 = __builtin_amdgcn_exp2f(p[5] * c);
            e2 = __builtin_amdgcn_exp2f(p[6] * c);
            e3 = __builtin_amdgcn_exp2f(p[7] * c);
            dd0 += e0; dd1 += e1; dd2 += e2; dd3 += e3;
            nn0 = fmaf(e0, p[4], nn0); nn1 = fmaf(e1, p[5], nn1);
            nn2 = fmaf(e2, p[6], nn2); nn3 = fmaf(e3, p[7], nn3);
            e0 = __builtin_amdgcn_exp2f(p[8] * c);
            e1 = __builtin_amdgcn_exp2f(p[9] * c);
            e2 = __builtin_amdgcn_exp2f(p[10] * c);
            e3 = __builtin_amdgcn_exp2f(p[11] * c);
            dd0 += e0; dd1 += e1; dd2 += e2; dd3 += e3;
            nn0 = fmaf(e0, p[8], nn0);  nn1 = fmaf(e1, p[9], nn1);
            nn2 = fmaf(e2, p[10], nn2); nn3 = fmaf(e3, p[11], nn3);
            e0 = __builtin_amdgcn_exp2f(p[12] * c);
            e1 = __builtin_amdgcn_exp2f(p[13] * c);
            e2 = __builtin_amdgcn_exp2f(p[14] * c);
            e3 = __builtin_amdgcn_exp2f(p[15] * c);
            dd0 += e0; dd1 += e1; dd2 += e2; dd3 += e3;
            nn0 = fmaf(e0, p[12], nn0); nn1 = fmaf(e1, p[13], nn1);
            nn2 = fmaf(e2, p[14], nn2); nn3 = fmaf(e3, p[15], nn3);

            float den = (dd0 + dd1) + (dd2 + dd3);
            float num = (nn0 + nn1) + (nn2 + nn3);
            den += __shfl_xor(den, 16); den += __shfl_xor(den, 32);
            num += __shfl_xor(num, 16); num += __shfl_xor(num, 32);
            sv = num * __builtin_amdgcn_rcpf(den);
            sn = sv * sv;
            sn += __shfl_xor(sn, 1); sn += __shfl_xor(sn, 2);
            sn += __shfl_xor(sn, 4); sn += __shfl_xor(sn, 8);
            factor = __builtin_amdgcn_sqrtf(sn)
                   * __builtin_amdgcn_rcpf(1.0f + sn);
            Vsum += sv * factor;
        }

        if (qB == 0)
            out[outbase + s * 128] = sv * factor;

        // ---- write-late: finish next tile (e=8..15), cvt, store x_t ----
        if (s < 7) {
            const float* xs = xsrc + (s + 1) * 8192;
            float sl8[8];
            sl8[0] = xs[512]; sl8[1] = xs[576]; sl8[2] = xs[640]; sl8[3] = xs[704];
            sl8[4] = xs[768]; sl8[5] = xs[832]; sl8[6] = xs[896]; sl8[7] = xs[960];
            unsigned h0 = (__float_as_uint(se[0]) >> 16) | hi_bits(se[1]);
            unsigned h1 = (__float_as_uint(se[2]) >> 16) | hi_bits(se[3]);
            unsigned h2 = (__float_as_uint(se[4]) >> 16) | hi_bits(se[5]);
            unsigned h3 = (__float_as_uint(se[6]) >> 16) | hi_bits(se[7]);
            unsigned l0 = (lo_u(se[0]) >> 16) | (lo_u(se[1]) & 0xFFFF0000u);
            unsigned l1 = (lo_u(se[2]) >> 16) | (lo_u(se[3]) & 0xFFFF0000u);
            unsigned l2 = (lo_u(se[4]) >> 16) | (lo_u(se[5]) & 0xFFFF0000u);
            unsigned l3 = (lo_u(se[6]) >> 16) | (lo_u(se[7]) & 0xFFFF0000u);
            unsigned h4 = (__float_as_uint(sl8[0]) >> 16) | hi_bits(sl8[1]);
            unsigned h5 = (__float_as_uint(sl8[2]) >> 16) | hi_bits(sl8[3]);
            unsigned h6 = (__float_as_uint(sl8[4]) >> 16) | hi_bits(sl8[5]);
            unsigned h7 = (__float_as_uint(sl8[6]) >> 16) | hi_bits(sl8[7]);
            unsigned l4 = (lo_u(sl8[0]) >> 16) | (lo_u(sl8[1]) & 0xFFFF0000u);
            unsigned l5 = (lo_u(sl8[2]) >> 16) | (lo_u(sl8[3]) & 0xFFFF0000u);
            unsigned l6 = (lo_u(sl8[4]) >> 16) | (lo_u(sl8[5]) & 0xFFFF0000u);
            unsigned l7 = (lo_u(sl8[6]) >> 16) | (lo_u(sl8[7]) & 0xFFFF0000u);
            *reinterpret_cast<uint4*>(xt_wr + ow00) = make_uint4(h0, h1, h2, h3);
            *reinterpret_cast<uint4*>(xt_wr + ow01) = make_uint4(l0, l1, l2, l3);
            *reinterpret_cast<uint4*>(xt_wr + ow10) = make_uint4(h4, h5, h6, h7);
            *reinterpret_cast<uint4*>(xt_wr + ow11) = make_uint4(l4, l5, l6, l7);
        }
        __syncthreads();            // p consumed & x_t(s+1) ready
    }
}

extern "C" void kernel_launch(void* const* d_in, const int* in_sizes, int n_in,
                              void* d_out, int out_size, void* d_ws, size_t ws_size,
                              hipStream_t stream) {
    const float* x  = (const float*)d_in[0];
    const float* rw = (const float*)d_in[1];
    const float* ns = (const float*)d_in[2];
    float* out = (float*)d_out;
    (void)in_sizes; (void)n_in; (void)out_size;

    const int grid = 32 * 32;       // blockIdx = o*32 + bc (64 b per block)
    const size_t w2_bytes = 32u * 64u * 16u * 16u * sizeof(float);  // 2 MB

    if (ws_size >= w2_bytes) {
        float* w2 = (float*)d_ws;
        wsum_kernel<<<512, 256, 0, stream>>>(rw, ns, w2);
        routing_kernel<true><<<grid, THREADS, 65536, stream>>>(x, w2, ns, out);
    } else {
        routing_kernel<false><<<grid, THREADS, 65536, stream>>>(x, rw, ns, out);
    }
}

// Round 17
// 77.840 us; speedup vs baseline: 1.3463x; 1.3463x over previous
//
#include <hip/hip_runtime.h>

// Capsule routing, MI355X. B=2048, I=64, O=32, DI=DO=16, 3 iters.
// R17 = R14 base (best verified: 76.6 us) + A-phase on v_pk_fma_f32.
// MFMA branch (R15/R16) abandoned: p-scatter conflicts + cvt overhead
// exceeded the ~14 us A-phase FMA cost it could save.
// Packed math: fp32 peak (157 TF) needs VOP3P v_pk_fma_f32 (2 FMA/lane/instr;
// scalar v_fma_f32 = ~103 TF, m07). A-phase packs over e-PAIRS:
//   acc2 = pk_fma((wq[2e],wq[2e+1]), (xv[2e],xv[2e+1]), acc2)
// both operand pairs are already register-adjacent (float4 loads), so the
// f32x2 views are free; 16 pk_fma + 2 h-adds per bb replace 32 fma.
// Inline asm (compiler never emits VOP3P fp32 from scalar code).
// Everything else R14 verbatim (all HW-verified):
//   NB=64/block (1024 blocks), W'=rw+ns precomputed to d_ws (wsum kernel),
//   quad-skewed x_t ([b']1056 + 16i + 4*(i>>3) + e; conflict-free under the
//   strided-8 phase model), swizzled p write/read, T14 split staging,
//   builtin exp2/rcp/sqrt, straight-line constant-indexed code,
//   no min-wave forcing.

#define THREADS 512

typedef __attribute__((ext_vector_type(2))) float f32x2;
typedef __attribute__((ext_vector_type(4))) float f32x4v;

__global__ __launch_bounds__(256) void wsum_kernel(
    const float* __restrict__ rw, const float* __restrict__ ns,
    float* __restrict__ w2)
{
    const int i = blockIdx.x * 256 + threadIdx.x;   // 131072 float4s
    const float4 a = reinterpret_cast<const float4*>(rw)[i];
    const float4 n = reinterpret_cast<const float4*>(ns)[i];
    float4 r;
    r.x = a.x + n.x;  r.y = a.y + n.y;  r.z = a.z + n.z;  r.w = a.w + n.w;
    reinterpret_cast<float4*>(w2)[i] = r;
}

__device__ __forceinline__ void pk_fma(f32x2& acc, f32x2 a, f32x2 b) {
    asm("v_pk_fma_f32 %0, %1, %2, %0" : "+v"(acc) : "v"(a), "v"(b));
}

template <bool PRE>
__global__ __launch_bounds__(THREADS) void routing_kernel(
    const float* __restrict__ x,    // (B, DI, I) = (2048,16,64)
    const float* __restrict__ rw,   // PRE ? W'=(rw+ns) : rw   (O,I,DO,DI)
    const float* __restrict__ ns,   // unused if PRE
    float* __restrict__ out)        // (1, O, B, DO)
{
    extern __shared__ float lds[];  // [0,8192) p; [8192,16640) x_t (skewed)
    float* xlds = lds + 8192;       // X(b',i,e) = b'*1056 + 16i + 4*(i>>3) + e

    const int tid  = threadIdx.x;
    const int w    = tid >> 6;      // wave 0..7
    const int lane = tid & 63;      // = i in A-phase

    const int o  = blockIdx.x >> 5;   // o-major: 32 consecutive blocks share W
    const int bc = blockIdx.x & 31;   // 64-b chunk
    const int bbase = bc * 64;

    // ---- W fragment as e-pairs: lane=i, d in {2w, 2w+1} (32 VGPR) ----
    f32x2 wp0[8], wp1[8];           // wp0[k] = (W[d0][2k], W[d0][2k+1])
    {
        const int base = (o * 64 + lane) * 256 + w * 32;
        #pragma unroll
        for (int eq = 0; eq < 4; ++eq) {
            if (PRE) {
                const float4 a0 = *reinterpret_cast<const float4*>(rw + base + eq * 4);
                wp0[2*eq]   = f32x2{a0.x, a0.y};
                wp0[2*eq+1] = f32x2{a0.z, a0.w};
                const float4 a1 = *reinterpret_cast<const float4*>(rw + base + 16 + eq * 4);
                wp1[2*eq]   = f32x2{a1.x, a1.y};
                wp1[2*eq+1] = f32x2{a1.z, a1.w};
            } else {
                const float4 a0 = *reinterpret_cast<const float4*>(rw + base + eq * 4);
                const float4 n0 = *reinterpret_cast<const float4*>(ns + base + eq * 4);
                wp0[2*eq]   = f32x2{a0.x + n0.x, a0.y + n0.y};
                wp0[2*eq+1] = f32x2{a0.z + n0.z, a0.w + n0.w};
                const float4 a1 = *reinterpret_cast<const float4*>(rw + base + 16 + eq * 4);
                const float4 n1 = *reinterpret_cast<const float4*>(ns + base + 16 + eq * 4);
                wp1[2*eq]   = f32x2{a1.x + n1.x, a1.y + n1.y};
                wp1[2*eq+1] = f32x2{a1.z + n1.z, a1.w + n1.w};
            }
        }
    }

    // ---- precomputed LDS addresses (R12-verified patterns) ----
    const int d0 = 2 * w, d1 = 2 * w + 1;
    float* pw0 = lds + d0 * 64 + ((((lane >> 2) ^ (d0 & 7)) << 2) | (lane & 3));
    float* pw1 = lds + d1 * 64 + ((((lane >> 2) ^ (d1 & 7)) << 2) | (lane & 3));

    const int qB  = lane >> 4;      // i-quarter 0..3
    const int dB  = lane & 15;
    const int swz = dB & 7;
    const float4* prbase = reinterpret_cast<const float4*>(lds) + (w * 16 + dB) * 16;
    const float4* pr0 = prbase + ((4 * qB + 0) ^ swz);
    const float4* pr1 = prbase + ((4 * qB + 1) ^ swz);
    const float4* pr2 = prbase + ((4 * qB + 2) ^ swz);
    const float4* pr3 = prbase + ((4 * qB + 3) ^ swz);

    // x_t reads (A-phase): lane = i; base quad-skewed by i>>3
    const float* xrb = xlds + lane * 16 + ((lane >> 3) << 2);

    // x_t writes (staging): thread holds (b=w, e=4k+ih, i=4il+m)
    const int il = lane & 15, ih = lane >> 4;
    float* xwb = xlds + w * 1056 + il * 64 + ((il >> 1) << 2) + ih;
    float* xw0 = xwb + 0;
    float* xw1 = xwb + 4;
    float* xw2 = xwb + 8;
    float* xw3 = xwb + 12;

    const float4* xsrc0 = reinterpret_cast<const float4*>(x) + bbase * 256
                        + (w * 256 + lane);

    const int outbase = (o * 2048 + bbase + w) * 16 + dB;

    // ---- prologue: stage x-tile 0 (transposed+skewed) ----
    float4 xb0 = xsrc0[0];
    float4 xb1 = xsrc0[64];
    float4 xb2 = xsrc0[128];
    float4 xb3 = xsrc0[192];
    xw0[0] = xb0.x;  xw0[16] = xb0.y;  xw0[32] = xb0.z;  xw0[48] = xb0.w;
    xw1[0] = xb1.x;  xw1[16] = xb1.y;  xw1[32] = xb1.z;  xw1[48] = xb1.w;
    xw2[0] = xb2.x;  xw2[16] = xb2.y;  xw2[32] = xb2.z;  xw2[48] = xb2.w;
    xw3[0] = xb3.x;  xw3[16] = xb3.y;  xw3[32] = xb3.z;  xw3[48] = xb3.w;
    __syncthreads();                // x-tile 0 ready

    #pragma unroll
    for (int s = 0; s < 8; ++s) {
        // ---- A-phase: x_t -> p (8 b's; 4 b128 reads, 16 pk_fma each) ----
        #pragma unroll
        for (int bb = 0; bb < 8; ++bb) {
            const f32x4v v0 = *reinterpret_cast<const f32x4v*>(xrb + bb * 1056 + 0);
            const f32x4v v1 = *reinterpret_cast<const f32x4v*>(xrb + bb * 1056 + 4);
            const f32x4v v2 = *reinterpret_cast<const f32x4v*>(xrb + bb * 1056 + 8);
            const f32x4v v3 = *reinterpret_cast<const f32x4v*>(xrb + bb * 1056 + 12);
            const f32x2 x0 = __builtin_shufflevector(v0, v0, 0, 1);
            const f32x2 x1 = __builtin_shufflevector(v0, v0, 2, 3);
            const f32x2 x2 = __builtin_shufflevector(v1, v1, 0, 1);
            const f32x2 x3 = __builtin_shufflevector(v1, v1, 2, 3);
            const f32x2 x4 = __builtin_shufflevector(v2, v2, 0, 1);
            const f32x2 x5 = __builtin_shufflevector(v2, v2, 2, 3);
            const f32x2 x6 = __builtin_shufflevector(v3, v3, 0, 1);
            const f32x2 x7 = __builtin_shufflevector(v3, v3, 2, 3);
            f32x2 acc0 = {0.f, 0.f};
            f32x2 acc1 = {0.f, 0.f};
            pk_fma(acc0, wp0[0], x0);  pk_fma(acc1, wp1[0], x0);
            pk_fma(acc0, wp0[1], x1);  pk_fma(acc1, wp1[1], x1);
            pk_fma(acc0, wp0[2], x2);  pk_fma(acc1, wp1[2], x2);
            pk_fma(acc0, wp0[3], x3);  pk_fma(acc1, wp1[3], x3);
            pk_fma(acc0, wp0[4], x4);  pk_fma(acc1, wp1[4], x4);
            pk_fma(acc0, wp0[5], x5);  pk_fma(acc1, wp1[5], x5);
            pk_fma(acc0, wp0[6], x6);  pk_fma(acc1, wp1[6], x6);
            pk_fma(acc0, wp0[7], x7);  pk_fma(acc1, wp1[7], x7);
            pw0[bb * 1024] = acc0[0] + acc0[1];
            pw1[bb * 1024] = acc1[0] + acc1[1];
        }
        __syncthreads();            // p ready; x_t free

        // ---- B-read: p[16] (i = qB*16 + 4jj + m) ----
        float p[16];
        {
            const float4 v0 = *pr0, v1 = *pr1, v2 = *pr2, v3 = *pr3;
            p[0]=v0.x; p[1]=v0.y; p[2]=v0.z; p[3]=v0.w;
            p[4]=v1.x; p[5]=v1.y; p[6]=v1.z; p[7]=v1.w;
            p[8]=v2.x; p[9]=v2.y; p[10]=v2.z; p[11]=v2.w;
            p[12]=v3.x; p[13]=v3.y; p[14]=v3.z; p[15]=v3.w;
        }

        // ---- T14 issue-early: next x-tile global loads ----
        if (s < 7) {
            const float4* xsrc = xsrc0 + (s + 1) * 2048;
            xb0 = xsrc[0];  xb1 = xsrc[64];  xb2 = xsrc[128];  xb3 = xsrc[192];
        }

        // ---- routing iterations ----
        float t0 = (p[0]+p[1]) + (p[2]+p[3]);
        float t1 = (p[4]+p[5]) + (p[6]+p[7]);
        float t2 = (p[8]+p[9]) + (p[10]+p[11]);
        float t3 = (p[12]+p[13]) + (p[14]+p[15]);
        float part = (t0 + t1) + (t2 + t3);
        part += __shfl_xor(part, 16);
        part += __shfl_xor(part, 32);
        float sv = part * (1.0f / 64.0f);

        float sn = sv * sv;         // squash norm over d (16-lane groups)
        sn += __shfl_xor(sn, 1); sn += __shfl_xor(sn, 2);
        sn += __shfl_xor(sn, 4); sn += __shfl_xor(sn, 8);
        float factor = __builtin_amdgcn_sqrtf(sn)
                     * __builtin_amdgcn_rcpf(1.0f + sn);
        float Vsum = sv * factor;

        #pragma unroll
        for (int it = 0; it < 2; ++it) {
            const float c = Vsum * 1.44269504089f;      // log2(e)
            float e0, e1, e2, e3;
            float dd0, dd1, dd2, dd3, nn0, nn1, nn2, nn3;
            e0 = __builtin_amdgcn_exp2f(p[0] * c);
            e1 = __builtin_amdgcn_exp2f(p[1] * c);
            e2 = __builtin_amdgcn_exp2f(p[2] * c);
            e3 = __builtin_amdgcn_exp2f(p[3] * c);
            dd0 = e0; dd1 = e1; dd2 = e2; dd3 = e3;
            nn0 = e0 * p[0]; nn1 = e1 * p[1]; nn2 = e2 * p[2]; nn3 = e3 * p[3];
            e0 = __builtin_amdgcn_exp2f(p[4] * c);
            e1 = __builtin_amdgcn_exp2f(p[5] * c);
            e2 = __builtin_amdgcn_exp2f(p[6] * c);
            e3 = __builtin_amdgcn_exp2f(p[7] * c);
            dd0 += e0; dd1 += e1; dd2 += e2; dd3 += e3;
            nn0 = fmaf(e0, p[4], nn0); nn1 = fmaf(e1, p[5], nn1);
            nn2 = fmaf(e2, p[6], nn2); nn3 = fmaf(e3, p[7], nn3);
            e0 = __builtin_amdgcn_exp2f(p[8] * c);
            e1 = __builtin_amdgcn_exp2f(p[9] * c);
            e2 = __builtin_amdgcn_exp2f(p[10] * c);
            e3 = __builtin_amdgcn_exp2f(p[11] * c);
            dd0 += e0; dd1 += e1; dd2 += e2; dd3 += e3;
            nn0 = fmaf(e0, p[8], nn0);  nn1 = fmaf(e1, p[9], nn1);
            nn2 = fmaf(e2, p[10], nn2); nn3 = fmaf(e3, p[11], nn3);
            e0 = __builtin_amdgcn_exp2f(p[12] * c);
            e1 = __builtin_amdgcn_exp2f(p[13] * c);
            e2 = __builtin_amdgcn_exp2f(p[14] * c);
            e3 = __builtin_amdgcn_exp2f(p[15] * c);
            dd0 += e0; dd1 += e1; dd2 += e2; dd3 += e3;
            nn0 = fmaf(e0, p[12], nn0); nn1 = fmaf(e1, p[13], nn1);
            nn2 = fmaf(e2, p[14], nn2); nn3 = fmaf(e3, p[15], nn3);

            float den = (dd0 + dd1) + (dd2 + dd3);
            float num = (nn0 + nn1) + (nn2 + nn3);
            den += __shfl_xor(den, 16); den += __shfl_xor(den, 32);
            num += __shfl_xor(num, 16); num += __shfl_xor(num, 32);
            sv = num * __builtin_amdgcn_rcpf(den);
            sn = sv * sv;
            sn += __shfl_xor(sn, 1); sn += __shfl_xor(sn, 2);
            sn += __shfl_xor(sn, 4); sn += __shfl_xor(sn, 8);
            factor = __builtin_amdgcn_sqrtf(sn)
                   * __builtin_amdgcn_rcpf(1.0f + sn);
            Vsum += sv * factor;
        }

        if (qB == 0)
            out[outbase + s * 128] = sv * factor;       // (1,O,B,DO), b=+8 per s

        // ---- T14 write-late: store next x-tile (transposed+skewed) ----
        if (s < 7) {
            xw0[0] = xb0.x;  xw0[16] = xb0.y;  xw0[32] = xb0.z;  xw0[48] = xb0.w;
            xw1[0] = xb1.x;  xw1[16] = xb1.y;  xw1[32] = xb1.z;  xw1[48] = xb1.w;
            xw2[0] = xb2.x;  xw2[16] = xb2.y;  xw2[32] = xb2.z;  xw2[48] = xb2.w;
            xw3[0] = xb3.x;  xw3[16] = xb3.y;  xw3[32] = xb3.z;  xw3[48] = xb3.w;
        }
        __syncthreads();            // p-reads done & next x-tile ready
    }
}

extern "C" void kernel_launch(void* const* d_in, const int* in_sizes, int n_in,
                              void* d_out, int out_size, void* d_ws, size_t ws_size,
                              hipStream_t stream) {
    const float* x  = (const float*)d_in[0];
    const float* rw = (const float*)d_in[1];
    const float* ns = (const float*)d_in[2];
    float* out = (float*)d_out;
    (void)in_sizes; (void)n_in; (void)out_size;

    const int grid = 32 * 32;       // blockIdx = o*32 + bc (64 b per block)
    const size_t w2_bytes = 32u * 64u * 16u * 16u * sizeof(float);  // 2 MB

    if (ws_size >= w2_bytes) {
        float* w2 = (float*)d_ws;
        wsum_kernel<<<512, 256, 0, stream>>>(rw, ns, w2);
        routing_kernel<true><<<grid, THREADS, 66560, stream>>>(x, w2, ns, out);
    } else {
        routing_kernel<false><<<grid, THREADS, 66560, stream>>>(x, rw, ns, out);
    }
}